// Round 15
// baseline (210.371 us; speedup 1.0000x reference)
//
#include <hip/hip_runtime.h>
#include <math.h>

#define B_   256
#define S_   200
#define NQ_  400
#define K_   4
#define M_   50
#define KD_  50
#define VD_  200
#define FD_  50
#define T_   (B_*S_)   // 51200 tokens
#define NE_  ((NQ_+1)*K_)   // 1604 distinct (q,r) rows

// ---------------------------------------------------------------------------
// kA1: corr LUT [401][50]. corr is a pure function of q.
// ---------------------------------------------------------------------------
__global__ __launch_bounds__(256) void kA1_corrlut(
    const float* __restrict__ q_tab, const float* __restrict__ key_mem,
    const float* __restrict__ W_qk, const float* __restrict__ b_qk,
    float* __restrict__ clut)
{
    const int wave = threadIdx.x >> 6;
    const int lane = threadIdx.x & 63;
    int qi = blockIdx.x * 4 + wave;
    const bool valid = (qi <= NQ_);
    if (qi > NQ_) qi = NQ_;

    __shared__ float sqk[4][KD_];
    const float* qe = q_tab + (size_t)qi * KD_;
    if (lane < KD_) {
        float acc = b_qk[lane];
#pragma unroll 10
        for (int k = 0; k < KD_; ++k)
            acc += qe[k] * W_qk[k * KD_ + lane];
        sqk[wave][lane] = tanhf(acc);
    }
    __syncthreads();

    float c = -INFINITY;
    if (lane < M_) {
        float acc = 0.0f;
#pragma unroll 10
        for (int k = 0; k < KD_; ++k)
            acc += sqk[wave][k] * key_mem[lane * KD_ + k];
        c = acc;
    }
    float mx = c;
#pragma unroll
    for (int off = 32; off; off >>= 1) mx = fmaxf(mx, __shfl_xor(mx, off));
    float e = (lane < M_) ? expf(c - mx) : 0.0f;
    float sm = e;
#pragma unroll
    for (int off = 32; off; off >>= 1) sm += __shfl_xor(sm, off);
    if (valid && lane < M_) clut[(size_t)qi * M_ + lane] = e / sm;
}

// ---------------------------------------------------------------------------
// kA2: erase/add LUT [1604][200]. One block per q, all 4 r-variants.
// ---------------------------------------------------------------------------
__global__ __launch_bounds__(256) void kA2_ealut(
    const float* __restrict__ W_v3, const float* __restrict__ b_v,
    const float* __restrict__ W_e, const float* __restrict__ b_e,
    const float* __restrict__ W_a, const float* __restrict__ b_a,
    float* __restrict__ elut, float* __restrict__ alut)
{
    __shared__ __align__(16) float sV[VD_][4];   // [k][r]
    const int qi  = blockIdx.x;                  // 0..400
    const int tid = threadIdx.x;
    const float qm = (qi > 0) ? 1.0f : 0.0f;
    int idx = qi - 1;
    if (idx < 0) idx = 0;

    float wc[4][4];
#pragma unroll
    for (int r = 0; r < 4; ++r)
#pragma unroll
        for (int k = 0; k < 4; ++k) {
            float dist = fabsf((float)k - (float)r) / (float)(K_ - 1);
            float w = 1.0f - dist;
            wc[r][k] = (w > 0.0f) ? w : 0.0f;
        }

    if (tid < VD_) {
        float w3[4];
#pragma unroll
        for (int k = 0; k < 4; ++k)
            w3[k] = W_v3[((size_t)k * NQ_ + idx) * VD_ + tid];
        float bv = b_v[tid];
#pragma unroll
        for (int r = 0; r < 4; ++r) {
            float s = wc[r][0]*w3[0] + wc[r][1]*w3[1] + wc[r][2]*w3[2] + wc[r][3]*w3[3];
            sV[tid][r] = bv + qm * s;
        }
    }
    __syncthreads();

    if (tid < VD_) {
        const int c = tid;
        float accE[4] = {0.f,0.f,0.f,0.f}, accA[4] = {0.f,0.f,0.f,0.f};
#pragma unroll 4
        for (int k = 0; k < VD_; ++k) {
            float we = W_e[(size_t)k * VD_ + c];
            float wa = W_a[(size_t)k * VD_ + c];
            float4 v = *(const float4*)&sV[k][0];
            float vv[4] = {v.x, v.y, v.z, v.w};
#pragma unroll
            for (int r = 0; r < 4; ++r) {
                accE[r] = fmaf(vv[r], we, accE[r]);
                accA[r] = fmaf(vv[r], wa, accA[r]);
            }
        }
        const float be = b_e[c], ba = b_a[c];
#pragma unroll
        for (int r = 0; r < 4; ++r) {
            const size_t row = (size_t)qi * K_ + r;
            elut[row * VD_ + c] = 1.0f / (1.0f + expf(-(accE[r] + be)));
            alut[row * VD_ + c] = tanhf(accA[r] + ba);
        }
    }
}

// ---------------------------------------------------------------------------
// kB v13: v6 structure + PACKED fp32 math (v_pk_fma_f32, 2 FMA/inst).
// Diagnosis chain: v6(1w)=108, v8(2w)=110, v10(scalar-fed)=118 -> kB is
// instruction-ISSUE-bound (~270 inst/step/SIMD, invariant under M-split);
// SMEM pipelining is impossible (out-of-order -> lgkmcnt(0) drains all).
// Fix the issue count itself: mem as 25 float2 pairs, 3 v_pk_fma_f32 per
// pair (gfx950 fp32 peak REQUIRES packed math; hipcc doesn't auto-pack).
// Structure: 256 thr, thread j owns all M=50 slots of column j; wall (corr)
// staged in LDS once (rows padded to 52 for 16B-aligned float4 reads,
// broadcast -> conflict-free); zero barriers in the loop; e/a 4-deep VMEM
// prefetch with LDS-sourced (in-order-waitable) addresses.
// ---------------------------------------------------------------------------
#define PK_FMA(d, s0, s1, s2) \
    asm("v_pk_fma_f32 %0, %1, %2, %3" : "=v"(d) : "v"(s0), "v"(s1), "v"(s2))
#define PK_FMA_ACC(acc, s0, s1) \
    asm("v_pk_fma_f32 %0, %1, %2, %0" : "+v"(acc) : "v"(s0), "v"(s1))
#define PK_FMA_NEG0(d, s0, s1, s2) \
    asm("v_pk_fma_f32 %0, %1, %2, %3 neg_lo:[1,0,0] neg_hi:[1,0,0]" \
        : "=v"(d) : "v"(s0), "v"(s1), "v"(s2))

__global__ __launch_bounds__(256) void kB_scan(
    const int* __restrict__ q_data, const int* __restrict__ r_data,
    const float* __restrict__ init_mem, const float* __restrict__ clut,
    const float* __restrict__ elut, const float* __restrict__ alut,
    float* __restrict__ reads)
{
    const int b   = blockIdx.x;
    const int tid = threadIdx.x;
    const int j   = tid;
    const bool act = (j < VD_);

    __shared__ int   sQ[S_], sR[S_];
    __shared__ __align__(16) float wall[S_][52];   // padded: 16B-aligned rows

    for (int i = tid; i < S_; i += 256) {
        sQ[i] = q_data[b * S_ + i];
        sR[i] = r_data[b * S_ + i];
    }
    __syncthreads();   // sQ visible for wall staging

    for (int i = tid; i < S_ * M_; i += 256) {
        int row = i / M_, col = i - row * M_;
        wall[row][col] = clut[(size_t)sQ[row] * M_ + col];
    }

    float2 mem2[25];
    if (act) {
#pragma unroll
        for (int i = 0; i < 25; ++i) {
            mem2[i].x = init_mem[(2*i)     * VD_ + j];
            mem2[i].y = init_mem[(2*i + 1) * VD_ + j];
        }
    }
    __syncthreads();   // wall visible — LAST barrier

    float* rb = reads + (size_t)b * S_ * VD_;

    // 4-deep e/a register pipeline (addresses from LDS sQ/sR: in-order waits)
    float e0=0,a0=0,e1=0,a1=0,e2=0,a2=0,e3=0,a3=0;
    if (act) {
        size_t i0 = (size_t)(sQ[0]*K_ + sR[0]) * VD_ + j;
        size_t i1 = (size_t)(sQ[1]*K_ + sR[1]) * VD_ + j;
        size_t i2 = (size_t)(sQ[2]*K_ + sR[2]) * VD_ + j;
        size_t i3 = (size_t)(sQ[3]*K_ + sR[3]) * VD_ + j;
        e0 = elut[i0]; a0 = alut[i0];
        e1 = elut[i1]; a1 = alut[i1];
        e2 = elut[i2]; a2 = alut[i2];
        e3 = elut[i3]; a3 = alut[i3];
    }

    for (int s = 0; s < S_; s += 2) {
        // prefetch e/a rows s+4, s+5 (consumed 2 iterations later)
        float e4=0,a4=0,e5=0,a5=0;
        if (act && s+4 < S_) {
            size_t i4 = (size_t)(sQ[s+4]*K_ + sR[s+4]) * VD_ + j;
            e4 = elut[i4]; a4 = alut[i4];
        }
        if (act && s+5 < S_) {
            size_t i5 = (size_t)(sQ[s+5]*K_ + sR[s+5]) * VD_ + j;
            e5 = alut ? elut[i5] : 0.f;  a5 = alut[i5];
        }

        // step s (packed: 3 pk_fma per float2 pair)
        {
            float2 ee; ee.x = e0; ee.y = e0;
            float2 aa; aa.x = a0; aa.y = a0;
            float2 racc; racc.x = 0.f; racc.y = 0.f;
            const float* w = &wall[s][0];
#pragma unroll
            for (int i = 0; i < 12; ++i) {
                float4 w4 = *(const float4*)&w[4*i];
                float2 wl; wl.x = w4.x; wl.y = w4.y;
                float2 wh; wh.x = w4.z; wh.y = w4.w;
                float2 t;
                PK_FMA_ACC(racc, wl, mem2[2*i]);
                PK_FMA_NEG0(t, ee, mem2[2*i], aa);
                PK_FMA_ACC(mem2[2*i], wl, t);
                PK_FMA_ACC(racc, wh, mem2[2*i+1]);
                PK_FMA_NEG0(t, ee, mem2[2*i+1], aa);
                PK_FMA_ACC(mem2[2*i+1], wh, t);
            }
            {   // tail pair (slots 48,49)
                float2 wp = *(const float2*)&w[48];
                float2 t;
                PK_FMA_ACC(racc, wp, mem2[24]);
                PK_FMA_NEG0(t, ee, mem2[24], aa);
                PK_FMA_ACC(mem2[24], wp, t);
            }
            if (act) rb[s * VD_ + j] = racc.x + racc.y;
        }
        // step s+1
        {
            float2 ee; ee.x = e1; ee.y = e1;
            float2 aa; aa.x = a1; aa.y = a1;
            float2 racc; racc.x = 0.f; racc.y = 0.f;
            const float* w = &wall[s+1][0];
#pragma unroll
            for (int i = 0; i < 12; ++i) {
                float4 w4 = *(const float4*)&w[4*i];
                float2 wl; wl.x = w4.x; wl.y = w4.y;
                float2 wh; wh.x = w4.z; wh.y = w4.w;
                float2 t;
                PK_FMA_ACC(racc, wl, mem2[2*i]);
                PK_FMA_NEG0(t, ee, mem2[2*i], aa);
                PK_FMA_ACC(mem2[2*i], wl, t);
                PK_FMA_ACC(racc, wh, mem2[2*i+1]);
                PK_FMA_NEG0(t, ee, mem2[2*i+1], aa);
                PK_FMA_ACC(mem2[2*i+1], wh, t);
            }
            {
                float2 wp = *(const float2*)&w[48];
                float2 t;
                PK_FMA_ACC(racc, wp, mem2[24]);
                PK_FMA_NEG0(t, ee, mem2[24], aa);
                PK_FMA_ACC(mem2[24], wp, t);
            }
            if (act) rb[(s+1) * VD_ + j] = racc.x + racc.y;
        }
        e0 = e2; a0 = a2; e1 = e3; a1 = a3;
        e2 = e4; a2 = a4; e3 = e5; a3 = a5;
    }
}

// ---------------------------------------------------------------------------
// k4a: summary GEMM (single reads buffer again). Writes summT[c][tok].
// ---------------------------------------------------------------------------
#define BT4A 40
__global__ __launch_bounds__(256) void k4a_summary(
    const int* __restrict__ q_data, const float* __restrict__ q_tab,
    const float* __restrict__ reads,
    const float* __restrict__ W_sum, const float* __restrict__ b_sum,
    float* __restrict__ summT)
{
    __shared__ __align__(16) float sAt[25][44];   // [kk][t], pad 44
    __shared__ __align__(16) float sW[25][52];
    __shared__ int sQ[BT4A];

    const int tid  = threadIdx.x;
    const int tok0 = blockIdx.x * BT4A;
    const int ty = tid / 25;        // 0..9 -> token group of 4
    const int tx = tid % 25;        // col pair
    const bool act = (tid < 250);
    const int t0 = ty * 4;

    if (tid < BT4A) sQ[tid] = q_data[tok0 + tid];

    float acc[4][2];
#pragma unroll
    for (int i = 0; i < 4; ++i) { acc[i][0] = 0.f; acc[i][1] = 0.f; }

    for (int kt = 0; kt < 250; kt += 25) {
        __syncthreads();
        for (int i = tid; i < BT4A * 25; i += 256) {
            int t = i / 25, kk = i % 25;
            float v;
            if (kt < VD_) v = reads[(size_t)(tok0 + t) * VD_ + kt + kk];
            else          v = q_tab[(size_t)sQ[t] * KD_ + (kt - VD_) + kk];
            sAt[kk][t] = v;
        }
        for (int i = tid; i < 25 * FD_; i += 256) {
            int kk = i / FD_, col = i % FD_;
            sW[kk][col] = W_sum[(size_t)(kt + kk) * FD_ + col];
        }
        __syncthreads();

        if (act) {
#pragma unroll 5
            for (int kk = 0; kk < 25; ++kk) {
                float2 w = *(const float2*)&sW[kk][2 * tx];
                float4 a0 = *(const float4*)&sAt[kk][t0];
                float av[4] = {a0.x, a0.y, a0.z, a0.w};
#pragma unroll
                for (int i = 0; i < 4; ++i) {
                    acc[i][0] = fmaf(av[i], w.x, acc[i][0]);
                    acc[i][1] = fmaf(av[i], w.y, acc[i][1]);
                }
            }
        }
    }

    if (act) {
        const float b0 = b_sum[2 * tx], b1 = b_sum[2 * tx + 1];
#pragma unroll
        for (int i = 0; i < 4; ++i) {
            const size_t tok = tok0 + t0 + i;
            summT[(size_t)(2 * tx)     * T_ + tok] = tanhf(acc[i][0] + b0);
            summT[(size_t)(2 * tx + 1) * T_ + tok] = tanhf(acc[i][1] + b1);
        }
    }
}

// ---------------------------------------------------------------------------
// k4b: per-token head. One thread per token.
// ---------------------------------------------------------------------------
__global__ __launch_bounds__(256) void k4b_head(
    const int* __restrict__ q_data, const float* __restrict__ q_tab,
    const float* __restrict__ summT,
    const float* __restrict__ W_ab, const float* __restrict__ b_ab,
    const float* __restrict__ W_th, const float* __restrict__ b_th,
    const float* __restrict__ W_disc, const float* __restrict__ b_disc,
    float* __restrict__ out)
{
    const int tok = blockIdx.x * 256 + threadIdx.x;
    const int q = q_data[tok];
    const float* qe = q_tab + (size_t)q * KD_;

    float v_ab = 0.f, v_d = 0.f, v_t0 = 0.f, v_t1 = 0.f, v_t2 = 0.f;
#pragma unroll 10
    for (int c = 0; c < FD_; ++c) {
        float s  = summT[(size_t)c * T_ + tok];
        float qv = qe[c];
        v_ab = fmaf(s,  W_ab[c],        v_ab);
        v_d  = fmaf(s,  W_disc[c],      v_d);
        v_d  = fmaf(qv, W_disc[FD_ + c], v_d);
        v_t0 = fmaf(qv, W_th[c * 3 + 0], v_t0);
        v_t1 = fmaf(qv, W_th[c * 3 + 1], v_t1);
        v_t2 = fmaf(qv, W_th[c * 3 + 2], v_t2);
    }

    float theta = 3.0f * (v_ab + b_ab[0]);
    float xd = v_d + b_disc[0];
    float alpha = fmaxf(xd, 0.0f) + log1pf(expf(-fabsf(xd)));
    float beta0 = tanhf(v_t0 + b_th[0]);
    float beta1 = tanhf(v_t1 + b_th[1]);
    float beta2 = tanhf(v_t2 + b_th[2]);
    float c1 = alpha * (theta - beta0);
    float c2 = c1 + alpha * (theta - beta1);
    float c3 = c2 + alpha * (theta - beta2);
    float mx = fmaxf(fmaxf(0.0f, c1), fmaxf(c2, c3));
    float e0 = expf(0.0f - mx), e1 = expf(c1 - mx),
          e2 = expf(c2 - mx), e3 = expf(c3 - mx);
    float s4 = e0 + e1 + e2 + e3;
    float4 o = make_float4(e0 / s4, e1 / s4, e2 / s4, e3 / s4);
    *(float4*)&out[(size_t)tok * 4] = o;
}

// ---------------------------------------------------------------------------
extern "C" void kernel_launch(void* const* d_in, const int* in_sizes, int n_in,
                              void* d_out, int out_size, void* d_ws, size_t ws_size,
                              hipStream_t stream) {
    const int*   q_data   = (const int*)  d_in[0];
    const int*   r_data   = (const int*)  d_in[1];
    const float* q_tab    = (const float*)d_in[2];
    const float* key_mem  = (const float*)d_in[3];
    const float* init_mem = (const float*)d_in[4];
    const float* W_qk     = (const float*)d_in[5];
    const float* b_qk     = (const float*)d_in[6];
    const float* W_v3     = (const float*)d_in[7];
    const float* b_v      = (const float*)d_in[8];
    const float* W_e      = (const float*)d_in[9];
    const float* b_e      = (const float*)d_in[10];
    const float* W_a      = (const float*)d_in[11];
    const float* b_a      = (const float*)d_in[12];
    const float* W_sum    = (const float*)d_in[13];
    const float* b_sum    = (const float*)d_in[14];
    const float* W_ab     = (const float*)d_in[15];
    const float* b_ab     = (const float*)d_in[16];
    const float* W_th     = (const float*)d_in[17];
    const float* b_th     = (const float*)d_in[18];
    const float* W_disc   = (const float*)d_in[19];
    const float* b_disc   = (const float*)d_in[20];

    float* ws    = (float*)d_ws;
    float* reads = ws;                                   // T*VD
    float* clut  = reads + (size_t)T_ * VD_;             // 401*50
    float* elut  = clut + (size_t)(NQ_ + 1) * M_;        // 1604*200
    float* alut  = elut + (size_t)NE_ * VD_;             // 1604*200
    float* summT = alut + (size_t)NE_ * VD_;             // 50*T
    // total ~13.5M floats = 54 MB

    kA1_corrlut<<<(NQ_ + 4) / 4, 256, 0, stream>>>(q_tab, key_mem, W_qk, b_qk, clut);
    kA2_ealut<<<NQ_ + 1, 256, 0, stream>>>(W_v3, b_v, W_e, b_e, W_a, b_a, elut, alut);
    kB_scan<<<B_, 256, 0, stream>>>(q_data, r_data, init_mem, clut, elut, alut, reads);
    k4a_summary<<<T_ / BT4A, 256, 0, stream>>>(q_data, q_tab, reads, W_sum, b_sum, summT);
    k4b_head<<<T_ / 256, 256, 0, stream>>>(q_data, q_tab, summT,
                                           W_ab, b_ab, W_th, b_th, W_disc, b_disc,
                                           (float*)d_out);
}

// Round 16
// 209.805 us; speedup vs baseline: 1.0027x; 1.0027x over previous
//
#include <hip/hip_runtime.h>
#include <math.h>

#define B_   256
#define S_   200
#define NQ_  400
#define K_   4
#define M_   50
#define KD_  50
#define VD_  200
#define FD_  50
#define T_   (B_*S_)   // 51200 tokens
#define NE_  ((NQ_+1)*K_)   // 1604 distinct (q,r) rows
#define CP_  52             // padded clut row stride (16B-aligned rows)

// ---------------------------------------------------------------------------
// kA1: corr LUT, PADDED rows [401][52] (cols 50,51 zeroed).
// ---------------------------------------------------------------------------
__global__ __launch_bounds__(256) void kA1_corrlut(
    const float* __restrict__ q_tab, const float* __restrict__ key_mem,
    const float* __restrict__ W_qk, const float* __restrict__ b_qk,
    float* __restrict__ clutP)
{
    const int wave = threadIdx.x >> 6;
    const int lane = threadIdx.x & 63;
    int qi = blockIdx.x * 4 + wave;
    const bool valid = (qi <= NQ_);
    if (qi > NQ_) qi = NQ_;

    __shared__ float sqk[4][KD_];
    const float* qe = q_tab + (size_t)qi * KD_;
    if (lane < KD_) {
        float acc = b_qk[lane];
#pragma unroll 10
        for (int k = 0; k < KD_; ++k)
            acc += qe[k] * W_qk[k * KD_ + lane];
        sqk[wave][lane] = tanhf(acc);
    }
    __syncthreads();

    float c = -INFINITY;
    if (lane < M_) {
        float acc = 0.0f;
#pragma unroll 10
        for (int k = 0; k < KD_; ++k)
            acc += sqk[wave][k] * key_mem[lane * KD_ + k];
        c = acc;
    }
    float mx = c;
#pragma unroll
    for (int off = 32; off; off >>= 1) mx = fmaxf(mx, __shfl_xor(mx, off));
    float e = (lane < M_) ? expf(c - mx) : 0.0f;
    float sm = e;
#pragma unroll
    for (int off = 32; off; off >>= 1) sm += __shfl_xor(sm, off);
    if (valid && lane < M_)  clutP[(size_t)qi * CP_ + lane] = e / sm;
    if (valid && lane >= M_ && lane < CP_) clutP[(size_t)qi * CP_ + lane] = 0.0f;
}

// ---------------------------------------------------------------------------
// kA2: erase/add LUT [1604][200]. One block per q, all 4 r-variants.
// ---------------------------------------------------------------------------
__global__ __launch_bounds__(256) void kA2_ealut(
    const float* __restrict__ W_v3, const float* __restrict__ b_v,
    const float* __restrict__ W_e, const float* __restrict__ b_e,
    const float* __restrict__ W_a, const float* __restrict__ b_a,
    float* __restrict__ elut, float* __restrict__ alut)
{
    __shared__ __align__(16) float sV[VD_][4];   // [k][r]
    const int qi  = blockIdx.x;                  // 0..400
    const int tid = threadIdx.x;
    const float qm = (qi > 0) ? 1.0f : 0.0f;
    int idx = qi - 1;
    if (idx < 0) idx = 0;

    float wc[4][4];
#pragma unroll
    for (int r = 0; r < 4; ++r)
#pragma unroll
        for (int k = 0; k < 4; ++k) {
            float dist = fabsf((float)k - (float)r) / (float)(K_ - 1);
            float w = 1.0f - dist;
            wc[r][k] = (w > 0.0f) ? w : 0.0f;
        }

    if (tid < VD_) {
        float w3[4];
#pragma unroll
        for (int k = 0; k < 4; ++k)
            w3[k] = W_v3[((size_t)k * NQ_ + idx) * VD_ + tid];
        float bv = b_v[tid];
#pragma unroll
        for (int r = 0; r < 4; ++r) {
            float s = wc[r][0]*w3[0] + wc[r][1]*w3[1] + wc[r][2]*w3[2] + wc[r][3]*w3[3];
            sV[tid][r] = bv + qm * s;
        }
    }
    __syncthreads();

    if (tid < VD_) {
        const int c = tid;
        float accE[4] = {0.f,0.f,0.f,0.f}, accA[4] = {0.f,0.f,0.f,0.f};
#pragma unroll 4
        for (int k = 0; k < VD_; ++k) {
            float we = W_e[(size_t)k * VD_ + c];
            float wa = W_a[(size_t)k * VD_ + c];
            float4 v = *(const float4*)&sV[k][0];
            float vv[4] = {v.x, v.y, v.z, v.w};
#pragma unroll
            for (int r = 0; r < 4; ++r) {
                accE[r] = fmaf(vv[r], we, accE[r]);
                accA[r] = fmaf(vv[r], wa, accA[r]);
            }
        }
        const float be = b_e[c], ba = b_a[c];
#pragma unroll
        for (int r = 0; r < 4; ++r) {
            const size_t row = (size_t)qi * K_ + r;
            elut[row * VD_ + c] = 1.0f / (1.0f + expf(-(accE[r] + be)));
            alut[row * VD_ + c] = tanhf(accA[r] + ba);
        }
    }
}

// ---------------------------------------------------------------------------
// kB v14: ALL loop feeds via VMEM (in-order, fine-grained-waitable pipe).
// Evidence: v6(LDS)=108, v8(2xTLP)=110, v10(SMEM)=118, v13(pk-asm)=145.
// Time invariant to TLP/per-wave work -> VALU-issue + LDS-pipe SUM is the
// wall; SMEM can't pipeline (OOO -> lgkmcnt(0) drains all). VMEM is the
// only untapped in-order pipe. w rows + q/r read as per-lane global loads
// with a divergence-faking zero (mbcnt(0,0)) so LLVM CANNOT scalarize them
// to s_load (v10's silent failure mode). All lanes share the address ->
// 1 L1 transaction/load. w banks reloaded IN PLACE mid-iteration so the
// vmcnt wait at next use sits behind a full compute phase. No LDS, no
// barriers, no SMEM in the loop.
// ---------------------------------------------------------------------------
__global__ __launch_bounds__(256, 1) void kB_scan(
    const int* __restrict__ q_data, const int* __restrict__ r_data,
    const float* __restrict__ init_mem, const float* __restrict__ clutP,
    const float* __restrict__ elut, const float* __restrict__ alut,
    float* __restrict__ reads)
{
    const int b   = blockIdx.x;
    const int j   = threadIdx.x;
    const bool act = (j < VD_);
    // divergence-faking zero: mbcnt result is divergent to the compiler,
    // value is 0 in every lane.
    const int dz = (int)__builtin_amdgcn_mbcnt_lo(0u, 0u);

    const int* qb = q_data + (size_t)b * S_;
    const int* rr = r_data + (size_t)b * S_;
    float* rout = reads + (size_t)b * S_ * VD_;

    float mem[M_];
    if (act) {
#pragma unroll
        for (int m = 0; m < M_; ++m) mem[m] = init_mem[m * VD_ + j];
    }

    // ---- prologue: q/r for rows 0..5, e/a rows 0..3, w rows 0,1 ----
    int pq0 = qb[0+dz], pr0 = rr[0+dz], pq1 = qb[1+dz], pr1 = rr[1+dz];
    int q2 = qb[2+dz], q3 = qb[3+dz];
    int tr2 = rr[2+dz], tr3 = rr[3+dz];
    int q4 = qb[4+dz], r4 = rr[4+dz], q5 = qb[5+dz], r5 = rr[5+dz];

    float e0=0,a0=0,e1=0,a1=0,e2=0,a2=0,e3=0,a3=0;
    if (act) {
        size_t i0 = (size_t)(pq0*K_ + pr0) * VD_ + j;
        size_t i1 = (size_t)(pq1*K_ + pr1) * VD_ + j;
        size_t i2 = (size_t)(q2*K_ + tr2) * VD_ + j;
        size_t i3 = (size_t)(q3*K_ + tr3) * VD_ + j;
        e0 = elut[i0]; a0 = alut[i0];
        e1 = elut[i1]; a1 = alut[i1];
        e2 = elut[i2]; a2 = alut[i2];
        e3 = elut[i3]; a3 = alut[i3];
    }

    float4 wA[13], wB[13];
    {
        const float* wr0 = clutP + (size_t)pq0 * CP_ + dz;
        const float* wr1 = clutP + (size_t)pq1 * CP_ + dz;
#pragma unroll
        for (int i = 0; i < 13; ++i) {
            wA[i] = *(const float4*)(wr0 + 4*i);
            wB[i] = *(const float4*)(wr1 + 4*i);
        }
    }

    for (int s = 0; s < S_; s += 2) {
        // q/r loads for rows s+6, s+7 (consumed after rotation)
        const int i6 = (s+6 < S_) ? s+6 : S_-1;
        const int i7 = (s+7 < S_) ? s+7 : S_-1;
        int q6 = qb[i6+dz], r6 = rr[i6+dz];
        int q7 = qb[i7+dz], r7 = rr[i7+dz];

        // e/a prefetch rows s+4, s+5 (consumed 2 iterations later)
        float e4=0,a4=0,e5=0,a5=0;
        if (act) {
            size_t i4 = (size_t)(q4*K_ + r4) * VD_ + j;
            size_t i5 = (size_t)(q5*K_ + r5) * VD_ + j;
            e4 = elut[i4]; a4 = alut[i4];
            e5 = elut[i5]; a5 = alut[i5];
        }

        // ---- step s (uses wA, e0/a0) ----
        {
            float ra = 0.f, rc = 0.f;
#pragma unroll
            for (int i = 0; i < 12; ++i) {
                const int m = 4*i;
                float4 w4 = wA[i];
                ra = fmaf(w4.x, mem[m], ra);
                float t0 = fmaf(-e0, mem[m], a0);
                mem[m] = fmaf(w4.x, t0, mem[m]);
                rc = fmaf(w4.y, mem[m+1], rc);
                float t1 = fmaf(-e0, mem[m+1], a0);
                mem[m+1] = fmaf(w4.y, t1, mem[m+1]);
                ra = fmaf(w4.z, mem[m+2], ra);
                float t2 = fmaf(-e0, mem[m+2], a0);
                mem[m+2] = fmaf(w4.z, t2, mem[m+2]);
                rc = fmaf(w4.w, mem[m+3], rc);
                float t3 = fmaf(-e0, mem[m+3], a0);
                mem[m+3] = fmaf(w4.w, t3, mem[m+3]);
            }
            {   // tail slots 48,49
                float4 w4 = wA[12];
                ra = fmaf(w4.x, mem[48], ra);
                float t0 = fmaf(-e0, mem[48], a0);
                mem[48] = fmaf(w4.x, t0, mem[48]);
                rc = fmaf(w4.y, mem[49], rc);
                float t1 = fmaf(-e0, mem[49], a0);
                mem[49] = fmaf(w4.y, t1, mem[49]);
            }
            if (act) rout[s * VD_ + j] = ra + rc;
        }

        // reload wA <- row q[s+2] (in place; next use is next iteration,
        // behind step s+1's full compute phase)
        {
            const float* wr = clutP + (size_t)q2 * CP_ + dz;
#pragma unroll
            for (int i = 0; i < 13; ++i) wA[i] = *(const float4*)(wr + 4*i);
        }

        // ---- step s+1 (uses wB, e1/a1) ----
        {
            float ra = 0.f, rc = 0.f;
#pragma unroll
            for (int i = 0; i < 12; ++i) {
                const int m = 4*i;
                float4 w4 = wB[i];
                ra = fmaf(w4.x, mem[m], ra);
                float t0 = fmaf(-e1, mem[m], a1);
                mem[m] = fmaf(w4.x, t0, mem[m]);
                rc = fmaf(w4.y, mem[m+1], rc);
                float t1 = fmaf(-e1, mem[m+1], a1);
                mem[m+1] = fmaf(w4.y, t1, mem[m+1]);
                ra = fmaf(w4.z, mem[m+2], ra);
                float t2 = fmaf(-e1, mem[m+2], a1);
                mem[m+2] = fmaf(w4.z, t2, mem[m+2]);
                rc = fmaf(w4.w, mem[m+3], rc);
                float t3 = fmaf(-e1, mem[m+3], a1);
                mem[m+3] = fmaf(w4.w, t3, mem[m+3]);
            }
            {
                float4 w4 = wB[12];
                ra = fmaf(w4.x, mem[48], ra);
                float t0 = fmaf(-e1, mem[48], a1);
                mem[48] = fmaf(w4.x, t0, mem[48]);
                rc = fmaf(w4.y, mem[49], rc);
                float t1 = fmaf(-e1, mem[49], a1);
                mem[49] = fmaf(w4.y, t1, mem[49]);
            }
            if (act) rout[(s+1) * VD_ + j] = ra + rc;
        }

        // reload wB <- row q[s+3]
        {
            const float* wr = clutP + (size_t)q3 * CP_ + dz;
#pragma unroll
            for (int i = 0; i < 13; ++i) wB[i] = *(const float4*)(wr + 4*i);
        }

        // rotate pipelines
        e0 = e2; a0 = a2; e1 = e3; a1 = a3;
        e2 = e4; a2 = a4; e3 = e5; a3 = a5;
        q2 = q4; q3 = q5; q4 = q6; q5 = q7;
        r4 = r6; r5 = r7;
    }
}

// ---------------------------------------------------------------------------
// k4a: summary GEMM. Writes summary transposed summT[c][tok].
// ---------------------------------------------------------------------------
#define BT4A 40
__global__ __launch_bounds__(256) void k4a_summary(
    const int* __restrict__ q_data, const float* __restrict__ q_tab,
    const float* __restrict__ reads,
    const float* __restrict__ W_sum, const float* __restrict__ b_sum,
    float* __restrict__ summT)
{
    __shared__ __align__(16) float sAt[25][44];   // [kk][t], pad 44
    __shared__ __align__(16) float sW[25][52];
    __shared__ int sQ[BT4A];

    const int tid  = threadIdx.x;
    const int tok0 = blockIdx.x * BT4A;
    const int ty = tid / 25;        // 0..9 -> token group of 4
    const int tx = tid % 25;        // col pair
    const bool act = (tid < 250);
    const int t0 = ty * 4;

    if (tid < BT4A) sQ[tid] = q_data[tok0 + tid];

    float acc[4][2];
#pragma unroll
    for (int i = 0; i < 4; ++i) { acc[i][0] = 0.f; acc[i][1] = 0.f; }

    for (int kt = 0; kt < 250; kt += 25) {
        __syncthreads();
        for (int i = tid; i < BT4A * 25; i += 256) {
            int t = i / 25, kk = i % 25;
            float v;
            if (kt < VD_) v = reads[(size_t)(tok0 + t) * VD_ + kt + kk];
            else          v = q_tab[(size_t)sQ[t] * KD_ + (kt - VD_) + kk];
            sAt[kk][t] = v;
        }
        for (int i = tid; i < 25 * FD_; i += 256) {
            int kk = i / FD_, col = i % FD_;
            sW[kk][col] = W_sum[(size_t)(kt + kk) * FD_ + col];
        }
        __syncthreads();

        if (act) {
#pragma unroll 5
            for (int kk = 0; kk < 25; ++kk) {
                float2 w = *(const float2*)&sW[kk][2 * tx];
                float4 a0 = *(const float4*)&sAt[kk][t0];
                float av[4] = {a0.x, a0.y, a0.z, a0.w};
#pragma unroll
                for (int i = 0; i < 4; ++i) {
                    acc[i][0] = fmaf(av[i], w.x, acc[i][0]);
                    acc[i][1] = fmaf(av[i], w.y, acc[i][1]);
                }
            }
        }
    }

    if (act) {
        const float b0 = b_sum[2 * tx], b1 = b_sum[2 * tx + 1];
#pragma unroll
        for (int i = 0; i < 4; ++i) {
            const size_t tok = tok0 + t0 + i;
            summT[(size_t)(2 * tx)     * T_ + tok] = tanhf(acc[i][0] + b0);
            summT[(size_t)(2 * tx + 1) * T_ + tok] = tanhf(acc[i][1] + b1);
        }
    }
}

// ---------------------------------------------------------------------------
// k4b: per-token head. One thread per token.
// ---------------------------------------------------------------------------
__global__ __launch_bounds__(256) void k4b_head(
    const int* __restrict__ q_data, const float* __restrict__ q_tab,
    const float* __restrict__ summT,
    const float* __restrict__ W_ab, const float* __restrict__ b_ab,
    const float* __restrict__ W_th, const float* __restrict__ b_th,
    const float* __restrict__ W_disc, const float* __restrict__ b_disc,
    float* __restrict__ out)
{
    const int tok = blockIdx.x * 256 + threadIdx.x;
    const int q = q_data[tok];
    const float* qe = q_tab + (size_t)q * KD_;

    float v_ab = 0.f, v_d = 0.f, v_t0 = 0.f, v_t1 = 0.f, v_t2 = 0.f;
#pragma unroll 10
    for (int c = 0; c < FD_; ++c) {
        float s  = summT[(size_t)c * T_ + tok];
        float qv = qe[c];
        v_ab = fmaf(s,  W_ab[c],        v_ab);
        v_d  = fmaf(s,  W_disc[c],      v_d);
        v_d  = fmaf(qv, W_disc[FD_ + c], v_d);
        v_t0 = fmaf(qv, W_th[c * 3 + 0], v_t0);
        v_t1 = fmaf(qv, W_th[c * 3 + 1], v_t1);
        v_t2 = fmaf(qv, W_th[c * 3 + 2], v_t2);
    }

    float theta = 3.0f * (v_ab + b_ab[0]);
    float xd = v_d + b_disc[0];
    float alpha = fmaxf(xd, 0.0f) + log1pf(expf(-fabsf(xd)));
    float beta0 = tanhf(v_t0 + b_th[0]);
    float beta1 = tanhf(v_t1 + b_th[1]);
    float beta2 = tanhf(v_t2 + b_th[2]);
    float c1 = alpha * (theta - beta0);
    float c2 = c1 + alpha * (theta - beta1);
    float c3 = c2 + alpha * (theta - beta2);
    float mx = fmaxf(fmaxf(0.0f, c1), fmaxf(c2, c3));
    float e0 = expf(0.0f - mx), e1 = expf(c1 - mx),
          e2 = expf(c2 - mx), e3 = expf(c3 - mx);
    float s4 = e0 + e1 + e2 + e3;
    float4 o = make_float4(e0 / s4, e1 / s4, e2 / s4, e3 / s4);
    *(float4*)&out[(size_t)tok * 4] = o;
}

// ---------------------------------------------------------------------------
extern "C" void kernel_launch(void* const* d_in, const int* in_sizes, int n_in,
                              void* d_out, int out_size, void* d_ws, size_t ws_size,
                              hipStream_t stream) {
    const int*   q_data   = (const int*)  d_in[0];
    const int*   r_data   = (const int*)  d_in[1];
    const float* q_tab    = (const float*)d_in[2];
    const float* key_mem  = (const float*)d_in[3];
    const float* init_mem = (const float*)d_in[4];
    const float* W_qk     = (const float*)d_in[5];
    const float* b_qk     = (const float*)d_in[6];
    const float* W_v3     = (const float*)d_in[7];
    const float* b_v      = (const float*)d_in[8];
    const float* W_e      = (const float*)d_in[9];
    const float* b_e      = (const float*)d_in[10];
    const float* W_a      = (const float*)d_in[11];
    const float* b_a      = (const float*)d_in[12];
    const float* W_sum    = (const float*)d_in[13];
    const float* b_sum    = (const float*)d_in[14];
    const float* W_ab     = (const float*)d_in[15];
    const float* b_ab     = (const float*)d_in[16];
    const float* W_th     = (const float*)d_in[17];
    const float* b_th     = (const float*)d_in[18];
    const float* W_disc   = (const float*)d_in[19];
    const float* b_disc   = (const float*)d_in[20];

    float* ws    = (float*)d_ws;
    float* reads = ws;                                   // T*VD
    float* clutP = reads + (size_t)T_ * VD_;             // 401*52
    float* elut  = clutP + (size_t)(NQ_ + 1) * CP_;      // 1604*200
    float* alut  = elut + (size_t)NE_ * VD_;             // 1604*200
    float* summT = alut + (size_t)NE_ * VD_;             // 50*T
    // total ~13.5M floats = 54 MB

    kA1_corrlut<<<(NQ_ + 4) / 4, 256, 0, stream>>>(q_tab, key_mem, W_qk, b_qk, clutP);
    kA2_ealut<<<NQ_ + 1, 256, 0, stream>>>(W_v3, b_v, W_e, b_e, W_a, b_a, elut, alut);
    kB_scan<<<B_, 256, 0, stream>>>(q_data, r_data, init_mem, clutP, elut, alut, reads);
    k4a_summary<<<T_ / BT4A, 256, 0, stream>>>(q_data, q_tab, reads, W_sum, b_sum, summT);
    k4b_head<<<T_ / 256, 256, 0, stream>>>(q_data, q_tab, summT,
                                           W_ab, b_ab, W_th, b_th, W_disc, b_disc,
                                           (float*)d_out);
}

// Round 17
// 150.786 us; speedup vs baseline: 1.3952x; 1.3914x over previous
//
#include <hip/hip_runtime.h>
#include <math.h>

#define B_   256
#define S_   200
#define NQ_  400
#define K_   4
#define M_   50
#define KD_  50
#define VD_  200
#define FD_  50
#define T_   (B_*S_)   // 51200 tokens
#define NE_  ((NQ_+1)*K_)   // 1604 distinct (q,r) rows
#define CP_  52             // padded clut row stride (16B-aligned rows)

// ---------------------------------------------------------------------------
// kA1: corr LUT, PADDED rows [401][52] (cols 50,51 zeroed).
// ---------------------------------------------------------------------------
__global__ __launch_bounds__(256) void kA1_corrlut(
    const float* __restrict__ q_tab, const float* __restrict__ key_mem,
    const float* __restrict__ W_qk, const float* __restrict__ b_qk,
    float* __restrict__ clutP)
{
    const int wave = threadIdx.x >> 6;
    const int lane = threadIdx.x & 63;
    int qi = blockIdx.x * 4 + wave;
    const bool valid = (qi <= NQ_);
    if (qi > NQ_) qi = NQ_;

    __shared__ float sqk[4][KD_];
    const float* qe = q_tab + (size_t)qi * KD_;
    if (lane < KD_) {
        float acc = b_qk[lane];
#pragma unroll 10
        for (int k = 0; k < KD_; ++k)
            acc += qe[k] * W_qk[k * KD_ + lane];
        sqk[wave][lane] = tanhf(acc);
    }
    __syncthreads();

    float c = -INFINITY;
    if (lane < M_) {
        float acc = 0.0f;
#pragma unroll 10
        for (int k = 0; k < KD_; ++k)
            acc += sqk[wave][k] * key_mem[lane * KD_ + k];
        c = acc;
    }
    float mx = c;
#pragma unroll
    for (int off = 32; off; off >>= 1) mx = fmaxf(mx, __shfl_xor(mx, off));
    float e = (lane < M_) ? expf(c - mx) : 0.0f;
    float sm = e;
#pragma unroll
    for (int off = 32; off; off >>= 1) sm += __shfl_xor(sm, off);
    if (valid && lane < M_)  clutP[(size_t)qi * CP_ + lane] = e / sm;
    if (valid && lane >= M_ && lane < CP_) clutP[(size_t)qi * CP_ + lane] = 0.0f;
}

// ---------------------------------------------------------------------------
// kA2: fused (e,a) LUT as float2 [1604][200]. One block per q, 4 r-variants.
// One float2 load per scan step instead of two float loads.
// ---------------------------------------------------------------------------
__global__ __launch_bounds__(256) void kA2_ealut(
    const float* __restrict__ W_v3, const float* __restrict__ b_v,
    const float* __restrict__ W_e, const float* __restrict__ b_e,
    const float* __restrict__ W_a, const float* __restrict__ b_a,
    float2* __restrict__ ea2)
{
    __shared__ __align__(16) float sV[VD_][4];   // [k][r]
    const int qi  = blockIdx.x;                  // 0..400
    const int tid = threadIdx.x;
    const float qm = (qi > 0) ? 1.0f : 0.0f;
    int idx = qi - 1;
    if (idx < 0) idx = 0;

    float wc[4][4];
#pragma unroll
    for (int r = 0; r < 4; ++r)
#pragma unroll
        for (int k = 0; k < 4; ++k) {
            float dist = fabsf((float)k - (float)r) / (float)(K_ - 1);
            float w = 1.0f - dist;
            wc[r][k] = (w > 0.0f) ? w : 0.0f;
        }

    if (tid < VD_) {
        float w3[4];
#pragma unroll
        for (int k = 0; k < 4; ++k)
            w3[k] = W_v3[((size_t)k * NQ_ + idx) * VD_ + tid];
        float bv = b_v[tid];
#pragma unroll
        for (int r = 0; r < 4; ++r) {
            float s = wc[r][0]*w3[0] + wc[r][1]*w3[1] + wc[r][2]*w3[2] + wc[r][3]*w3[3];
            sV[tid][r] = bv + qm * s;
        }
    }
    __syncthreads();

    if (tid < VD_) {
        const int c = tid;
        float accE[4] = {0.f,0.f,0.f,0.f}, accA[4] = {0.f,0.f,0.f,0.f};
#pragma unroll 4
        for (int k = 0; k < VD_; ++k) {
            float we = W_e[(size_t)k * VD_ + c];
            float wa = W_a[(size_t)k * VD_ + c];
            float4 v = *(const float4*)&sV[k][0];
            float vv[4] = {v.x, v.y, v.z, v.w};
#pragma unroll
            for (int r = 0; r < 4; ++r) {
                accE[r] = fmaf(vv[r], we, accE[r]);
                accA[r] = fmaf(vv[r], wa, accA[r]);
            }
        }
        const float be = b_e[c], ba = b_a[c];
#pragma unroll
        for (int r = 0; r < 4; ++r) {
            const size_t row = (size_t)qi * K_ + r;
            float ev = 1.0f / (1.0f + expf(-(accE[r] + be)));
            float av = tanhf(accA[r] + ba);
            ea2[row * VD_ + c] = make_float2(ev, av);
        }
    }
}

// ---------------------------------------------------------------------------
// kB v15: iteration-granularity double-buffered register banks, NO rotation.
// Theory: all prior variants (LDS=108/SMEM=118/VMEM=138/2xTLP=110) share a
// 2-step-ahead rotated-register prefetch; if vmcnt placement is conservative
// across the rotation, every iteration eats a full L2 round-trip (~the
// observed 1000cy/iter gap). Here: 16-step unroll, two 8-step (e,a) banks;
// bank X is reloaded IN PLACE right after its consuming half and next
// consumed a full half (~2600cy of FMA issue) later. 1 float2 load/step,
// eids prefetched one half ahead, w via broadcast float4 from LDS wall,
// zero barriers/SMEM in the loop.
// ---------------------------------------------------------------------------
__global__ __launch_bounds__(256, 1) void kB_scan(
    const int* __restrict__ q_data, const int* __restrict__ r_data,
    const float* __restrict__ init_mem, const float* __restrict__ clutP,
    const float2* __restrict__ ea2, float* __restrict__ reads)
{
    const int b   = blockIdx.x;
    const int tid = threadIdx.x;
    const int j   = tid;
    const bool act = (j < VD_);

    __shared__ int sE[S_];
    __shared__ __align__(16) float wall[S_][CP_];

    for (int i = tid; i < S_; i += 256)
        sE[i] = q_data[(size_t)b * S_ + i] * K_ + r_data[(size_t)b * S_ + i];
    __syncthreads();   // sE visible
    for (int i = tid; i < S_ * CP_; i += 256) {
        int row = i / CP_, col = i - row * CP_;
        wall[row][col] = clutP[(size_t)(sE[row] >> 2) * CP_ + col];
    }
    float mem[M_];
    if (act) {
#pragma unroll
        for (int m = 0; m < M_; ++m) mem[m] = init_mem[m * VD_ + j];
    }
    __syncthreads();   // wall visible — LAST barrier

    float* rout = reads + (size_t)b * S_ * VD_;

    // (e,a) banks for steps [16k,16k+8) = bank A, [16k+8,16k+16) = bank B
    float eA[8], aA[8], eB[8], aB[8];
    if (act) {
#pragma unroll
        for (int h = 0; h < 8; ++h) {
            float2 v = ea2[(size_t)sE[h] * VD_ + j];
            eA[h] = v.x; aA[h] = v.y;
        }
#pragma unroll
        for (int h = 0; h < 8; ++h) {
            float2 v = ea2[(size_t)sE[8 + h] * VD_ + j];
            eB[h] = v.x; aB[h] = v.y;
        }
    }

#define SCAN_STEP(ST, EV, AV)                                        \
    {                                                                \
        const float* w_ = &wall[(ST)][0];                            \
        float ra = 0.f, rc = 0.f;                                    \
        _Pragma("unroll")                                            \
        for (int i_ = 0; i_ < 12; ++i_) {                            \
            const int m_ = 4 * i_;                                   \
            float4 w4 = *(const float4*)&w_[4 * i_];                 \
            ra = fmaf(w4.x, mem[m_], ra);                            \
            float t0 = fmaf(-(EV), mem[m_], (AV));                   \
            mem[m_] = fmaf(w4.x, t0, mem[m_]);                       \
            rc = fmaf(w4.y, mem[m_+1], rc);                          \
            float t1 = fmaf(-(EV), mem[m_+1], (AV));                 \
            mem[m_+1] = fmaf(w4.y, t1, mem[m_+1]);                   \
            ra = fmaf(w4.z, mem[m_+2], ra);                          \
            float t2 = fmaf(-(EV), mem[m_+2], (AV));                 \
            mem[m_+2] = fmaf(w4.z, t2, mem[m_+2]);                   \
            rc = fmaf(w4.w, mem[m_+3], rc);                          \
            float t3 = fmaf(-(EV), mem[m_+3], (AV));                 \
            mem[m_+3] = fmaf(w4.w, t3, mem[m_+3]);                   \
        }                                                            \
        {                                                            \
            float4 w4 = *(const float4*)&w_[48];                     \
            ra = fmaf(w4.x, mem[48], ra);                            \
            float t0 = fmaf(-(EV), mem[48], (AV));                   \
            mem[48] = fmaf(w4.x, t0, mem[48]);                       \
            rc = fmaf(w4.y, mem[49], rc);                            \
            float t1 = fmaf(-(EV), mem[49], (AV));                   \
            mem[49] = fmaf(w4.y, t1, mem[49]);                       \
        }                                                            \
        if (act) rout[(size_t)(ST) * VD_ + j] = ra + rc;             \
    }

    for (int k = 0; k < 12; ++k) {
        const int s0 = 16 * k;

        // ---- half A: consume bank A (steps s0..s0+7) ----
        int eidAn[8];
#pragma unroll
        for (int h = 0; h < 8; ++h) {
            int idx = s0 + 16 + h; if (idx > S_ - 1) idx = S_ - 1;
            eidAn[h] = sE[idx];
        }
#pragma unroll
        for (int h = 0; h < 8; ++h) SCAN_STEP(s0 + h, eA[h], aA[h]);
        // reload bank A in place for steps s0+16..s0+23 (consumed next k,
        // a full half (~2600cy of FMA issue) later)
        if (act) {
#pragma unroll
            for (int h = 0; h < 8; ++h) {
                float2 v = ea2[(size_t)eidAn[h] * VD_ + j];
                eA[h] = v.x; aA[h] = v.y;
            }
        }

        // ---- half B: consume bank B (steps s0+8..s0+15) ----
        int eidBn[8];
#pragma unroll
        for (int h = 0; h < 8; ++h) {
            int idx = s0 + 24 + h; if (idx > S_ - 1) idx = S_ - 1;
            eidBn[h] = sE[idx];
        }
#pragma unroll
        for (int h = 0; h < 8; ++h) SCAN_STEP(s0 + 8 + h, eB[h], aB[h]);
        if (act) {
#pragma unroll
            for (int h = 0; h < 8; ++h) {
                float2 v = ea2[(size_t)eidBn[h] * VD_ + j];
                eB[h] = v.x; aB[h] = v.y;
            }
        }
    }
    // epilogue: steps 192..199 consume bank A (reloaded at k=11 half A)
#pragma unroll
    for (int h = 0; h < 8; ++h) SCAN_STEP(192 + h, eA[h], aA[h]);
#undef SCAN_STEP
}

// ---------------------------------------------------------------------------
// k4a: summary GEMM. Writes summary transposed summT[c][tok].
// ---------------------------------------------------------------------------
#define BT4A 40
__global__ __launch_bounds__(256) void k4a_summary(
    const int* __restrict__ q_data, const float* __restrict__ q_tab,
    const float* __restrict__ reads,
    const float* __restrict__ W_sum, const float* __restrict__ b_sum,
    float* __restrict__ summT)
{
    __shared__ __align__(16) float sAt[25][44];   // [kk][t], pad 44
    __shared__ __align__(16) float sW[25][52];
    __shared__ int sQ[BT4A];

    const int tid  = threadIdx.x;
    const int tok0 = blockIdx.x * BT4A;
    const int ty = tid / 25;        // 0..9 -> token group of 4
    const int tx = tid % 25;        // col pair
    const bool act = (tid < 250);
    const int t0 = ty * 4;

    if (tid < BT4A) sQ[tid] = q_data[tok0 + tid];

    float acc[4][2];
#pragma unroll
    for (int i = 0; i < 4; ++i) { acc[i][0] = 0.f; acc[i][1] = 0.f; }

    for (int kt = 0; kt < 250; kt += 25) {
        __syncthreads();
        for (int i = tid; i < BT4A * 25; i += 256) {
            int t = i / 25, kk = i % 25;
            float v;
            if (kt < VD_) v = reads[(size_t)(tok0 + t) * VD_ + kt + kk];
            else          v = q_tab[(size_t)sQ[t] * KD_ + (kt - VD_) + kk];
            sAt[kk][t] = v;
        }
        for (int i = tid; i < 25 * FD_; i += 256) {
            int kk = i / FD_, col = i % FD_;
            sW[kk][col] = W_sum[(size_t)(kt + kk) * FD_ + col];
        }
        __syncthreads();

        if (act) {
#pragma unroll 5
            for (int kk = 0; kk < 25; ++kk) {
                float2 w = *(const float2*)&sW[kk][2 * tx];
                float4 a0 = *(const float4*)&sAt[kk][t0];
                float av[4] = {a0.x, a0.y, a0.z, a0.w};
#pragma unroll
                for (int i = 0; i < 4; ++i) {
                    acc[i][0] = fmaf(av[i], w.x, acc[i][0]);
                    acc[i][1] = fmaf(av[i], w.y, acc[i][1]);
                }
            }
        }
    }

    if (act) {
        const float b0 = b_sum[2 * tx], b1 = b_sum[2 * tx + 1];
#pragma unroll
        for (int i = 0; i < 4; ++i) {
            const size_t tok = tok0 + t0 + i;
            summT[(size_t)(2 * tx)     * T_ + tok] = tanhf(acc[i][0] + b0);
            summT[(size_t)(2 * tx + 1) * T_ + tok] = tanhf(acc[i][1] + b1);
        }
    }
}

// ---------------------------------------------------------------------------
// k4b: per-token head. One thread per token.
// ---------------------------------------------------------------------------
__global__ __launch_bounds__(256) void k4b_head(
    const int* __restrict__ q_data, const float* __restrict__ q_tab,
    const float* __restrict__ summT,
    const float* __restrict__ W_ab, const float* __restrict__ b_ab,
    const float* __restrict__ W_th, const float* __restrict__ b_th,
    const float* __restrict__ W_disc, const float* __restrict__ b_disc,
    float* __restrict__ out)
{
    const int tok = blockIdx.x * 256 + threadIdx.x;
    const int q = q_data[tok];
    const float* qe = q_tab + (size_t)q * KD_;

    float v_ab = 0.f, v_d = 0.f, v_t0 = 0.f, v_t1 = 0.f, v_t2 = 0.f;
#pragma unroll 10
    for (int c = 0; c < FD_; ++c) {
        float s  = summT[(size_t)c * T_ + tok];
        float qv = qe[c];
        v_ab = fmaf(s,  W_ab[c],        v_ab);
        v_d  = fmaf(s,  W_disc[c],      v_d);
        v_d  = fmaf(qv, W_disc[FD_ + c], v_d);
        v_t0 = fmaf(qv, W_th[c * 3 + 0], v_t0);
        v_t1 = fmaf(qv, W_th[c * 3 + 1], v_t1);
        v_t2 = fmaf(qv, W_th[c * 3 + 2], v_t2);
    }

    float theta = 3.0f * (v_ab + b_ab[0]);
    float xd = v_d + b_disc[0];
    float alpha = fmaxf(xd, 0.0f) + log1pf(expf(-fabsf(xd)));
    float beta0 = tanhf(v_t0 + b_th[0]);
    float beta1 = tanhf(v_t1 + b_th[1]);
    float beta2 = tanhf(v_t2 + b_th[2]);
    float c1 = alpha * (theta - beta0);
    float c2 = c1 + alpha * (theta - beta1);
    float c3 = c2 + alpha * (theta - beta2);
    float mx = fmaxf(fmaxf(0.0f, c1), fmaxf(c2, c3));
    float e0 = expf(0.0f - mx), e1 = expf(c1 - mx),
          e2 = expf(c2 - mx), e3 = expf(c3 - mx);
    float s4 = e0 + e1 + e2 + e3;
    float4 o = make_float4(e0 / s4, e1 / s4, e2 / s4, e3 / s4);
    *(float4*)&out[(size_t)tok * 4] = o;
}

// ---------------------------------------------------------------------------
extern "C" void kernel_launch(void* const* d_in, const int* in_sizes, int n_in,
                              void* d_out, int out_size, void* d_ws, size_t ws_size,
                              hipStream_t stream) {
    const int*   q_data   = (const int*)  d_in[0];
    const int*   r_data   = (const int*)  d_in[1];
    const float* q_tab    = (const float*)d_in[2];
    const float* key_mem  = (const float*)d_in[3];
    const float* init_mem = (const float*)d_in[4];
    const float* W_qk     = (const float*)d_in[5];
    const float* b_qk     = (const float*)d_in[6];
    const float* W_v3     = (const float*)d_in[7];
    const float* b_v      = (const float*)d_in[8];
    const float* W_e      = (const float*)d_in[9];
    const float* b_e      = (const float*)d_in[10];
    const float* W_a      = (const float*)d_in[11];
    const float* b_a      = (const float*)d_in[12];
    const float* W_sum    = (const float*)d_in[13];
    const float* b_sum    = (const float*)d_in[14];
    const float* W_ab     = (const float*)d_in[15];
    const float* b_ab     = (const float*)d_in[16];
    const float* W_th     = (const float*)d_in[17];
    const float* b_th     = (const float*)d_in[18];
    const float* W_disc   = (const float*)d_in[19];
    const float* b_disc   = (const float*)d_in[20];

    float* ws    = (float*)d_ws;
    float* reads = ws;                                    // T*VD = 10.24M
    float* clutP = reads + (size_t)T_ * VD_;              // 401*52
    float* ea2f  = clutP + (size_t)(NQ_ + 1) * CP_;       // 1604*200*2 (float2)
    float* summT = ea2f + (size_t)NE_ * VD_ * 2;          // 50*T
    // total ~13.5M floats = 54 MB

    kA1_corrlut<<<(NQ_ + 4) / 4, 256, 0, stream>>>(q_tab, key_mem, W_qk, b_qk, clutP);
    kA2_ealut<<<NQ_ + 1, 256, 0, stream>>>(W_v3, b_v, W_e, b_e, W_a, b_a,
                                           (float2*)ea2f);
    kB_scan<<<B_, 256, 0, stream>>>(q_data, r_data, init_mem, clutP,
                                    (const float2*)ea2f, reads);
    k4a_summary<<<T_ / BT4A, 256, 0, stream>>>(q_data, q_tab, reads, W_sum, b_sum, summT);
    k4b_head<<<T_ / 256, 256, 0, stream>>>(q_data, q_tab, summT,
                                           W_ab, b_ab, W_th, b_th, W_disc, b_disc,
                                           (float*)d_out);
}

// Round 18
// 149.699 us; speedup vs baseline: 1.4053x; 1.0073x over previous
//
#include <hip/hip_runtime.h>
#include <math.h>

#define B_   256
#define S_   200
#define NQ_  400
#define K_   4
#define M_   50
#define KD_  50
#define VD_  200
#define FD_  50
#define T_   (B_*S_)   // 51200 tokens
#define NE_  ((NQ_+1)*K_)   // 1604 distinct (q,r) rows
#define CP_  52             // padded clut row stride (16B-aligned rows)

// ---------------------------------------------------------------------------
// kA1: corr LUT, PADDED rows [401][52] (cols 50,51 zeroed).
// ---------------------------------------------------------------------------
__global__ __launch_bounds__(256) void kA1_corrlut(
    const float* __restrict__ q_tab, const float* __restrict__ key_mem,
    const float* __restrict__ W_qk, const float* __restrict__ b_qk,
    float* __restrict__ clutP)
{
    const int wave = threadIdx.x >> 6;
    const int lane = threadIdx.x & 63;
    int qi = blockIdx.x * 4 + wave;
    const bool valid = (qi <= NQ_);
    if (qi > NQ_) qi = NQ_;

    __shared__ float sqk[4][KD_];
    const float* qe = q_tab + (size_t)qi * KD_;
    if (lane < KD_) {
        float acc = b_qk[lane];
#pragma unroll 10
        for (int k = 0; k < KD_; ++k)
            acc += qe[k] * W_qk[k * KD_ + lane];
        sqk[wave][lane] = tanhf(acc);
    }
    __syncthreads();

    float c = -INFINITY;
    if (lane < M_) {
        float acc = 0.0f;
#pragma unroll 10
        for (int k = 0; k < KD_; ++k)
            acc += sqk[wave][k] * key_mem[lane * KD_ + k];
        c = acc;
    }
    float mx = c;
#pragma unroll
    for (int off = 32; off; off >>= 1) mx = fmaxf(mx, __shfl_xor(mx, off));
    float e = (lane < M_) ? expf(c - mx) : 0.0f;
    float sm = e;
#pragma unroll
    for (int off = 32; off; off >>= 1) sm += __shfl_xor(sm, off);
    if (valid && lane < M_)  clutP[(size_t)qi * CP_ + lane] = e / sm;
    if (valid && lane >= M_ && lane < CP_) clutP[(size_t)qi * CP_ + lane] = 0.0f;
}

// ---------------------------------------------------------------------------
// kA2: fused (e,a) LUT as float2 [1604][200]. One block per q, 4 r-variants.
// ---------------------------------------------------------------------------
__global__ __launch_bounds__(256) void kA2_ealut(
    const float* __restrict__ W_v3, const float* __restrict__ b_v,
    const float* __restrict__ W_e, const float* __restrict__ b_e,
    const float* __restrict__ W_a, const float* __restrict__ b_a,
    float2* __restrict__ ea2)
{
    __shared__ __align__(16) float sV[VD_][4];   // [k][r]
    const int qi  = blockIdx.x;                  // 0..400
    const int tid = threadIdx.x;
    const float qm = (qi > 0) ? 1.0f : 0.0f;
    int idx = qi - 1;
    if (idx < 0) idx = 0;

    float wc[4][4];
#pragma unroll
    for (int r = 0; r < 4; ++r)
#pragma unroll
        for (int k = 0; k < 4; ++k) {
            float dist = fabsf((float)k - (float)r) / (float)(K_ - 1);
            float w = 1.0f - dist;
            wc[r][k] = (w > 0.0f) ? w : 0.0f;
        }

    if (tid < VD_) {
        float w3[4];
#pragma unroll
        for (int k = 0; k < 4; ++k)
            w3[k] = W_v3[((size_t)k * NQ_ + idx) * VD_ + tid];
        float bv = b_v[tid];
#pragma unroll
        for (int r = 0; r < 4; ++r) {
            float s = wc[r][0]*w3[0] + wc[r][1]*w3[1] + wc[r][2]*w3[2] + wc[r][3]*w3[3];
            sV[tid][r] = bv + qm * s;
        }
    }
    __syncthreads();

    if (tid < VD_) {
        const int c = tid;
        float accE[4] = {0.f,0.f,0.f,0.f}, accA[4] = {0.f,0.f,0.f,0.f};
#pragma unroll 4
        for (int k = 0; k < VD_; ++k) {
            float we = W_e[(size_t)k * VD_ + c];
            float wa = W_a[(size_t)k * VD_ + c];
            float4 v = *(const float4*)&sV[k][0];
            float vv[4] = {v.x, v.y, v.z, v.w};
#pragma unroll
            for (int r = 0; r < 4; ++r) {
                accE[r] = fmaf(vv[r], we, accE[r]);
                accA[r] = fmaf(vv[r], wa, accA[r]);
            }
        }
        const float be = b_e[c], ba = b_a[c];
#pragma unroll
        for (int r = 0; r < 4; ++r) {
            const size_t row = (size_t)qi * K_ + r;
            float ev = 1.0f / (1.0f + expf(-(accE[r] + be)));
            float av = tanhf(accA[r] + ba);
            ea2[row * VD_ + c] = make_float2(ev, av);
        }
    }
}

// ---------------------------------------------------------------------------
// kB v16: v15 + register-prefetched wall rows (the last in-step feed).
// v15 left ~900cy/step unexplained; e/a is 8-deep prefetched, LDS pipe is
// ~150cy/step -> the exposure is the IN-STEP ds_read_b128 of wall (each
// read covered by only ~24cy of FMA before its use). Fix with the v15
// discipline applied to w: two banks wv0/wv1 (bank = step parity), bank p
// reloaded IN PLACE right after step ST consumes it (<- wall[ST+2]);
// load-to-use distance = one full step (~300cy FMA) > 120cy LDS latency.
// No rotation. VGPR ~200 is fine at __launch_bounds__(256,1) (budget 512).
// ---------------------------------------------------------------------------
__global__ __launch_bounds__(256, 1) void kB_scan(
    const int* __restrict__ q_data, const int* __restrict__ r_data,
    const float* __restrict__ init_mem, const float* __restrict__ clutP,
    const float2* __restrict__ ea2, float* __restrict__ reads)
{
    const int b   = blockIdx.x;
    const int tid = threadIdx.x;
    const int j   = tid;
    const bool act = (j < VD_);

    __shared__ int sE[S_];
    __shared__ __align__(16) float wall[S_][CP_];

    for (int i = tid; i < S_; i += 256)
        sE[i] = q_data[(size_t)b * S_ + i] * K_ + r_data[(size_t)b * S_ + i];
    __syncthreads();   // sE visible
    for (int i = tid; i < S_ * CP_; i += 256) {
        int row = i / CP_, col = i - row * CP_;
        wall[row][col] = clutP[(size_t)(sE[row] >> 2) * CP_ + col];
    }
    float mem[M_];
    if (act) {
#pragma unroll
        for (int m = 0; m < M_; ++m) mem[m] = init_mem[m * VD_ + j];
    }
    __syncthreads();   // wall visible — LAST barrier

    float* rout = reads + (size_t)b * S_ * VD_;

    // (e,a) banks for steps [16k,16k+8) = bank A, [16k+8,16k+16) = bank B
    float eA[8], aA[8], eB[8], aB[8];
    if (act) {
#pragma unroll
        for (int h = 0; h < 8; ++h) {
            float2 v = ea2[(size_t)sE[h] * VD_ + j];
            eA[h] = v.x; aA[h] = v.y;
        }
#pragma unroll
        for (int h = 0; h < 8; ++h) {
            float2 v = ea2[(size_t)sE[8 + h] * VD_ + j];
            eB[h] = v.x; aB[h] = v.y;
        }
    }

    // w register banks: bank0 = even steps, bank1 = odd steps.
    float4 wv0[13], wv1[13];
#pragma unroll
    for (int i = 0; i < 13; ++i) {
        wv0[i] = *(const float4*)&wall[0][4*i];
        wv1[i] = *(const float4*)&wall[1][4*i];
    }

// consume bank WB for step ST, then reload WB <- wall[min(ST+2,S-1)]
#define SCAN_STEP(ST, EV, AV, WB)                                    \
    {                                                                \
        float ra = 0.f, rc = 0.f;                                    \
        _Pragma("unroll")                                            \
        for (int i_ = 0; i_ < 12; ++i_) {                            \
            const int m_ = 4 * i_;                                   \
            float4 w4 = WB[i_];                                      \
            ra = fmaf(w4.x, mem[m_], ra);                            \
            float t0 = fmaf(-(EV), mem[m_], (AV));                   \
            mem[m_] = fmaf(w4.x, t0, mem[m_]);                       \
            rc = fmaf(w4.y, mem[m_+1], rc);                          \
            float t1 = fmaf(-(EV), mem[m_+1], (AV));                 \
            mem[m_+1] = fmaf(w4.y, t1, mem[m_+1]);                   \
            ra = fmaf(w4.z, mem[m_+2], ra);                          \
            float t2 = fmaf(-(EV), mem[m_+2], (AV));                 \
            mem[m_+2] = fmaf(w4.z, t2, mem[m_+2]);                   \
            rc = fmaf(w4.w, mem[m_+3], rc);                          \
            float t3 = fmaf(-(EV), mem[m_+3], (AV));                 \
            mem[m_+3] = fmaf(w4.w, t3, mem[m_+3]);                   \
        }                                                            \
        {                                                            \
            float4 w4 = WB[12];                                      \
            ra = fmaf(w4.x, mem[48], ra);                            \
            float t0 = fmaf(-(EV), mem[48], (AV));                   \
            mem[48] = fmaf(w4.x, t0, mem[48]);                       \
            rc = fmaf(w4.y, mem[49], rc);                            \
            float t1 = fmaf(-(EV), mem[49], (AV));                   \
            mem[49] = fmaf(w4.y, t1, mem[49]);                       \
        }                                                            \
        if (act) rout[(size_t)(ST) * VD_ + j] = ra + rc;             \
        {                                                            \
            const int nr_ = ((ST) + 2 < S_) ? (ST) + 2 : S_ - 1;     \
            const float* wr_ = &wall[nr_][0];                        \
            _Pragma("unroll")                                        \
            for (int i_ = 0; i_ < 13; ++i_)                          \
                WB[i_] = *(const float4*)(wr_ + 4 * i_);             \
        }                                                            \
    }

    for (int k = 0; k < 12; ++k) {
        const int s0 = 16 * k;

        // ---- half A: consume e/a bank A (steps s0..s0+7) ----
        int eidAn[8];
#pragma unroll
        for (int h = 0; h < 8; ++h) {
            int idx = s0 + 16 + h; if (idx > S_ - 1) idx = S_ - 1;
            eidAn[h] = sE[idx];
        }
#pragma unroll
        for (int h = 0; h < 8; ++h) {
            if ((h & 1) == 0) { SCAN_STEP(s0 + h, eA[h], aA[h], wv0); }
            else              { SCAN_STEP(s0 + h, eA[h], aA[h], wv1); }
        }
        if (act) {
#pragma unroll
            for (int h = 0; h < 8; ++h) {
                float2 v = ea2[(size_t)eidAn[h] * VD_ + j];
                eA[h] = v.x; aA[h] = v.y;
            }
        }

        // ---- half B: consume e/a bank B (steps s0+8..s0+15) ----
        int eidBn[8];
#pragma unroll
        for (int h = 0; h < 8; ++h) {
            int idx = s0 + 24 + h; if (idx > S_ - 1) idx = S_ - 1;
            eidBn[h] = sE[idx];
        }
#pragma unroll
        for (int h = 0; h < 8; ++h) {
            if ((h & 1) == 0) { SCAN_STEP(s0 + 8 + h, eB[h], aB[h], wv0); }
            else              { SCAN_STEP(s0 + 8 + h, eB[h], aB[h], wv1); }
        }
        if (act) {
#pragma unroll
            for (int h = 0; h < 8; ++h) {
                float2 v = ea2[(size_t)eidBn[h] * VD_ + j];
                eB[h] = v.x; aB[h] = v.y;
            }
        }
    }
    // epilogue: steps 192..199 consume e/a bank A (reloaded at k=11 half A)
#pragma unroll
    for (int h = 0; h < 8; ++h) {
        if ((h & 1) == 0) { SCAN_STEP(192 + h, eA[h], aA[h], wv0); }
        else              { SCAN_STEP(192 + h, eA[h], aA[h], wv1); }
    }
#undef SCAN_STEP
}

// ---------------------------------------------------------------------------
// k4a: summary GEMM. Writes summary transposed summT[c][tok].
// ---------------------------------------------------------------------------
#define BT4A 40
__global__ __launch_bounds__(256) void k4a_summary(
    const int* __restrict__ q_data, const float* __restrict__ q_tab,
    const float* __restrict__ reads,
    const float* __restrict__ W_sum, const float* __restrict__ b_sum,
    float* __restrict__ summT)
{
    __shared__ __align__(16) float sAt[25][44];   // [kk][t], pad 44
    __shared__ __align__(16) float sW[25][52];
    __shared__ int sQ[BT4A];

    const int tid  = threadIdx.x;
    const int tok0 = blockIdx.x * BT4A;
    const int ty = tid / 25;        // 0..9 -> token group of 4
    const int tx = tid % 25;        // col pair
    const bool act = (tid < 250);
    const int t0 = ty * 4;

    if (tid < BT4A) sQ[tid] = q_data[tok0 + tid];

    float acc[4][2];
#pragma unroll
    for (int i = 0; i < 4; ++i) { acc[i][0] = 0.f; acc[i][1] = 0.f; }

    for (int kt = 0; kt < 250; kt += 25) {
        __syncthreads();
        for (int i = tid; i < BT4A * 25; i += 256) {
            int t = i / 25, kk = i % 25;
            float v;
            if (kt < VD_) v = reads[(size_t)(tok0 + t) * VD_ + kt + kk];
            else          v = q_tab[(size_t)sQ[t] * KD_ + (kt - VD_) + kk];
            sAt[kk][t] = v;
        }
        for (int i = tid; i < 25 * FD_; i += 256) {
            int kk = i / FD_, col = i % FD_;
            sW[kk][col] = W_sum[(size_t)(kt + kk) * FD_ + col];
        }
        __syncthreads();

        if (act) {
#pragma unroll 5
            for (int kk = 0; kk < 25; ++kk) {
                float2 w = *(const float2*)&sW[kk][2 * tx];
                float4 a0 = *(const float4*)&sAt[kk][t0];
                float av[4] = {a0.x, a0.y, a0.z, a0.w};
#pragma unroll
                for (int i = 0; i < 4; ++i) {
                    acc[i][0] = fmaf(av[i], w.x, acc[i][0]);
                    acc[i][1] = fmaf(av[i], w.y, acc[i][1]);
                }
            }
        }
    }

    if (act) {
        const float b0 = b_sum[2 * tx], b1 = b_sum[2 * tx + 1];
#pragma unroll
        for (int i = 0; i < 4; ++i) {
            const size_t tok = tok0 + t0 + i;
            summT[(size_t)(2 * tx)     * T_ + tok] = tanhf(acc[i][0] + b0);
            summT[(size_t)(2 * tx + 1) * T_ + tok] = tanhf(acc[i][1] + b1);
        }
    }
}

// ---------------------------------------------------------------------------
// k4b: per-token head. One thread per token.
// ---------------------------------------------------------------------------
__global__ __launch_bounds__(256) void k4b_head(
    const int* __restrict__ q_data, const float* __restrict__ q_tab,
    const float* __restrict__ summT,
    const float* __restrict__ W_ab, const float* __restrict__ b_ab,
    const float* __restrict__ W_th, const float* __restrict__ b_th,
    const float* __restrict__ W_disc, const float* __restrict__ b_disc,
    float* __restrict__ out)
{
    const int tok = blockIdx.x * 256 + threadIdx.x;
    const int q = q_data[tok];
    const float* qe = q_tab + (size_t)q * KD_;

    float v_ab = 0.f, v_d = 0.f, v_t0 = 0.f, v_t1 = 0.f, v_t2 = 0.f;
#pragma unroll 10
    for (int c = 0; c < FD_; ++c) {
        float s  = summT[(size_t)c * T_ + tok];
        float qv = qe[c];
        v_ab = fmaf(s,  W_ab[c],        v_ab);
        v_d  = fmaf(s,  W_disc[c],      v_d);
        v_d  = fmaf(qv, W_disc[FD_ + c], v_d);
        v_t0 = fmaf(qv, W_th[c * 3 + 0], v_t0);
        v_t1 = fmaf(qv, W_th[c * 3 + 1], v_t1);
        v_t2 = fmaf(qv, W_th[c * 3 + 2], v_t2);
    }

    float theta = 3.0f * (v_ab + b_ab[0]);
    float xd = v_d + b_disc[0];
    float alpha = fmaxf(xd, 0.0f) + log1pf(expf(-fabsf(xd)));
    float beta0 = tanhf(v_t0 + b_th[0]);
    float beta1 = tanhf(v_t1 + b_th[1]);
    float beta2 = tanhf(v_t2 + b_th[2]);
    float c1 = alpha * (theta - beta0);
    float c2 = c1 + alpha * (theta - beta1);
    float c3 = c2 + alpha * (theta - beta2);
    float mx = fmaxf(fmaxf(0.0f, c1), fmaxf(c2, c3));
    float e0 = expf(0.0f - mx), e1 = expf(c1 - mx),
          e2 = expf(c2 - mx), e3 = expf(c3 - mx);
    float s4 = e0 + e1 + e2 + e3;
    float4 o = make_float4(e0 / s4, e1 / s4, e2 / s4, e3 / s4);
    *(float4*)&out[(size_t)tok * 4] = o;
}

// ---------------------------------------------------------------------------
extern "C" void kernel_launch(void* const* d_in, const int* in_sizes, int n_in,
                              void* d_out, int out_size, void* d_ws, size_t ws_size,
                              hipStream_t stream) {
    const int*   q_data   = (const int*)  d_in[0];
    const int*   r_data   = (const int*)  d_in[1];
    const float* q_tab    = (const float*)d_in[2];
    const float* key_mem  = (const float*)d_in[3];
    const float* init_mem = (const float*)d_in[4];
    const float* W_qk     = (const float*)d_in[5];
    const float* b_qk     = (const float*)d_in[6];
    const float* W_v3     = (const float*)d_in[7];
    const float* b_v      = (const float*)d_in[8];
    const float* W_e      = (const float*)d_in[9];
    const float* b_e      = (const float*)d_in[10];
    const float* W_a      = (const float*)d_in[11];
    const float* b_a      = (const float*)d_in[12];
    const float* W_sum    = (const float*)d_in[13];
    const float* b_sum    = (const float*)d_in[14];
    const float* W_ab     = (const float*)d_in[15];
    const float* b_ab     = (const float*)d_in[16];
    const float* W_th     = (const float*)d_in[17];
    const float* b_th     = (const float*)d_in[18];
    const float* W_disc   = (const float*)d_in[19];
    const float* b_disc   = (const float*)d_in[20];

    float* ws    = (float*)d_ws;
    float* reads = ws;                                    // T*VD = 10.24M
    float* clutP = reads + (size_t)T_ * VD_;              // 401*52
    float* ea2f  = clutP + (size_t)(NQ_ + 1) * CP_;       // 1604*200*2 (float2)
    float* summT = ea2f + (size_t)NE_ * VD_ * 2;          // 50*T
    // total ~13.5M floats = 54 MB

    kA1_corrlut<<<(NQ_ + 4) / 4, 256, 0, stream>>>(q_tab, key_mem, W_qk, b_qk, clutP);
    kA2_ealut<<<NQ_ + 1, 256, 0, stream>>>(W_v3, b_v, W_e, b_e, W_a, b_a,
                                           (float2*)ea2f);
    kB_scan<<<B_, 256, 0, stream>>>(q_data, r_data, init_mem, clutP,
                                    (const float2*)ea2f, reads);
    k4a_summary<<<T_ / BT4A, 256, 0, stream>>>(q_data, q_tab, reads, W_sum, b_sum, summT);
    k4b_head<<<T_ / 256, 256, 0, stream>>>(q_data, q_tab, summT,
                                           W_ab, b_ab, W_th, b_th, W_disc, b_disc,
                                           (float*)d_out);
}